// Round 15
// baseline (386.650 us; speedup 1.0000x reference)
//
#include <hip/hip_runtime.h>

#define DIN 1024
#define DE  1024
#define SEQ 2048
#define NB  8

typedef __bf16 bf16x8 __attribute__((ext_vector_type(8)));
typedef float  f32x4  __attribute__((ext_vector_type(4)));
typedef unsigned short u16;
typedef u16 u16x8 __attribute__((ext_vector_type(8)));
typedef u16 u16x4 __attribute__((ext_vector_type(4)));

__device__ __forceinline__ u16 f2bf(float f) {
  unsigned u = __builtin_bit_cast(unsigned, f);
  return (u16)((u + 0x7FFFu + ((u >> 16) & 1u)) >> 16);
}
__device__ __forceinline__ float bf2f(u16 h) {
  return __builtin_bit_cast(float, (unsigned)h << 16);
}

typedef __attribute__((address_space(1))) const unsigned char g_u8;
typedef __attribute__((address_space(3))) unsigned char l_u8;
__device__ __forceinline__ void gload16(const void* g, void* l) {
  __builtin_amdgcn_global_load_lds((g_u8*)g, (l_u8*)l, 16, 0, 0);
}

// ---------------- convert fp32 -> bf16 (vectorized) ----------------
__global__ __launch_bounds__(256) void cvt_f32_bf16(const float* __restrict__ in,
                                                    u16* __restrict__ out, int n4) {
  int i = blockIdx.x * 256 + threadIdx.x;
  if (i >= n4) return;
  float4 v = ((const float4*)in)[i];
  u16x4 o;
  o[0] = f2bf(v.x); o[1] = f2bf(v.y); o[2] = f2bf(v.z); o[3] = f2bf(v.w);
  ((u16x4*)out)[i] = o;
}

// ------- transpose 4 weights [K=1024][N=1024] fp32 -> Wt [N][K] bf16, one launch -------
__global__ __launch_bounds__(256) void transpose_w4(
    const float* __restrict__ W0, const float* __restrict__ W1,
    const float* __restrict__ W2, const float* __restrict__ W3,
    u16* __restrict__ Wt) {
  __shared__ float t[32][33];
  const int tx = threadIdx.x, ty = threadIdx.y;
  const int bx = blockIdx.x * 32, by = blockIdx.y * 32;
  const int w = blockIdx.z;
  const float* W = w == 0 ? W0 : w == 1 ? W1 : w == 2 ? W2 : W3;
  u16* Wtw = Wt + (size_t)w * 1048576;
#pragma unroll
  for (int i = 0; i < 4; ++i)
    t[ty + i * 8][tx] = W[(size_t)(by + ty + i * 8) * 1024 + bx + tx];
  __syncthreads();
#pragma unroll
  for (int i = 0; i < 4; ++i)
    Wtw[(size_t)(bx + ty + i * 8) * 1024 + by + tx] = f2bf(t[tx][ty + i * 8]);
}

// ---------------- in-place row softmax on bf16 [rows][2048] ----------------
__global__ __launch_bounds__(256) void softmax_rows_bf16(u16* __restrict__ P) {
  const size_t row = blockIdx.x;
  u16* pr = P + row * 2048 + (size_t)threadIdx.x * 8;
  u16x8 v = *(const u16x8*)pr;
  float x[8];
#pragma unroll
  for (int j = 0; j < 8; ++j) x[j] = bf2f(v[j]);
  float m = x[0];
#pragma unroll
  for (int j = 1; j < 8; ++j) m = fmaxf(m, x[j]);
#pragma unroll
  for (int off = 32; off; off >>= 1) m = fmaxf(m, __shfl_xor(m, off));
  __shared__ float rm[4], rs[4];
  const int lane = threadIdx.x & 63, wid = threadIdx.x >> 6;
  if (lane == 0) rm[wid] = m;
  __syncthreads();
  m = fmaxf(fmaxf(rm[0], rm[1]), fmaxf(rm[2], rm[3]));
  float s = 0.f;
#pragma unroll
  for (int j = 0; j < 8; ++j) { x[j] = __expf(x[j] - m); s += x[j]; }
#pragma unroll
  for (int off = 32; off; off >>= 1) s += __shfl_xor(s, off);
  if (lane == 0) rs[wid] = s;
  __syncthreads();
  s = (rs[0] + rs[1]) + (rs[2] + rs[3]);
  const float inv = 1.f / s;
  u16x8 o;
#pragma unroll
  for (int j = 0; j < 8; ++j) o[j] = f2bf(x[j] * inv);
  *(u16x8*)pr = o;
}

// ============ m201-style phase-scheduled GEMM: C = A[M,K] * Bt[N,K]^T ============
// 256x256 tile, BK=64, double-buffered LDS, 8 waves (2Mx4N), phases of
// {ds_read ∥ stage half-tile -> s_barrier -> lgkmcnt(0) -> 16 MFMA -> s_barrier},
// one counted vmcnt(6) per K-tile (0 only at drain). XOR-swizzled LDS via
// pre-swizzled global staging source (0 bank conflicts, r6-r14).
// Register note: 112 VGPR + 128 AGPR = 240 <= 256 -> 2 waves/SIMD, 1 block/CU.
// OMODE: 0=fp32, 1=bf16, 4=QKV trio (blockIdx.z selects weight/bias/output;
// z=0 -> Cv row-major, z=1 -> C1 row-major, z=2 -> C2 scattered Vt[b][col][s]).
template <int BMT, int OMODE, bool HAS_BIAS>
__global__ __launch_bounds__(512, 1) void gemmph(
    const u16* __restrict__ A, const u16* __restrict__ Bt, void* __restrict__ Cv,
    const float* __restrict__ bias, int M, int N, int K,
    size_t sA, size_t sB, size_t sC, float scale,
    u16* __restrict__ C1, u16* __restrict__ C2,
    const float* __restrict__ b1, const float* __restrict__ b2) {
  constexpr int ABYTES = BMT * 128;
  constexpr int AHALF  = ABYTES / 2;
  constexpr int BUFB   = ABYTES + 32768;
  constexpr int LA     = AHALF / 8192;
  constexpr int MR     = BMT / 32;
  __shared__ __align__(16) char lds8[2 * BUFB];
  const int tid = threadIdx.x, lane = tid & 63, wid = tid >> 6;
  const int wm = wid >> 2, wn = wid & 3;
  const int lane15 = lane & 15, gk = lane >> 4;

  const int gx = gridDim.x, gy = gridDim.y;
  int lin = blockIdx.x + gx * (blockIdx.y + gy * blockIdx.z);
  const int nwg = gx * gy * (int)gridDim.z;
  const int q = nwg >> 3, r8 = nwg & 7;
  const int xcd = lin & 7, idx = lin >> 3;
  lin = (xcd < r8 ? xcd * (q + 1) : r8 * (q + 1) + (xcd - r8) * q) + idx;
  const int bz = lin / (gx * gy);
  const int rem = lin - bz * (gx * gy);
  const int by = rem / gx, bx = rem - (rem / gx) * gx;

  const char* Ag = (const char*)(A + (size_t)bz * sA + (size_t)by * BMT * K);
  const u16* Btz = (OMODE == 4) ? Bt + (size_t)bz * 1048576 : Bt + (size_t)bz * sB;
  const char* Bg = (const char*)(Btz + (size_t)bx * 256 * K);
  const size_t Kb = (size_t)K * 2;

  const int spr = tid >> 3;
  const int sg = (tid & 7) ^ (spr & 7);
  const char* srcA[2][2];
  const char* srcB[2][2];
#pragma unroll
  for (int h = 0; h < 2; ++h) {
#pragma unroll
    for (int j = 0; j < LA; ++j)
      srcA[h][j] = Ag + (size_t)(h * (BMT / 2) + j * 64 + spr) * Kb + sg * 16;
#pragma unroll
    for (int j = 0; j < 2; ++j)
      srcB[h][j] = Bg + (size_t)(h * 128 + j * 64 + spr) * Kb + sg * 16;
  }

  auto stageA2 = [&](int dbuf) {
#pragma unroll
    for (int h = 0; h < 2; ++h) {
      char* d = lds8 + dbuf * BUFB + h * AHALF + tid * 16;
#pragma unroll
      for (int j = 0; j < LA; ++j) { gload16(srcA[h][j], d + j * 8192); srcA[h][j] += 128; }
    }
  };
  auto stageB1 = [&](int h, int dbuf) {
    char* d = lds8 + dbuf * BUFB + ABYTES + h * 16384 + tid * 16;
    gload16(srcB[h][0], d);        srcB[h][0] += 128;
    gload16(srcB[h][1], d + 8192); srcB[h][1] += 128;
  };

  const int arow = lane15 * 128 + ((gk ^ (lane15 & 7)) << 4);

  f32x4 acc[MR][4] = {};
  const int NT = K >> 6;

  stageA2(0); stageB1(0, 0); stageB1(1, 0);
  stageB1(0, 1); stageA2(1);
  asm volatile("s_waitcnt vmcnt(6)" ::: "memory");
  __builtin_amdgcn_s_barrier();
  __builtin_amdgcn_sched_barrier(0);

  for (int kt = 0; kt < NT; ++kt) {
    const char* Ab = lds8 + (kt & 1) * BUFB + wm * AHALF;
    const char* Bb = lds8 + (kt & 1) * BUFB + ABYTES + (wn >> 1) * 16384 + (wn & 1) * 8192;
    const int nbuf = (kt + 1) & 1;
    const int cbuf = kt & 1;
    bf16x8 af[4][2], bfr[4][2];

    // ---- P0: reads A(m0-3)+B(n0-1) [12]; stage B1(kt+1); MFMA q(0,0) ----
#pragma unroll
    for (int m = 0; m < 4; ++m) {
      af[m][0] = *(const bf16x8*)(Ab + m * 2048 + arow);
      af[m][1] = *(const bf16x8*)(Ab + m * 2048 + (arow ^ 64));
    }
#pragma unroll
    for (int n = 0; n < 2; ++n) {
      bfr[n][0] = *(const bf16x8*)(Bb + n * 2048 + arow);
      bfr[n][1] = *(const bf16x8*)(Bb + n * 2048 + (arow ^ 64));
    }
    if (kt + 1 < NT) stageB1(1, nbuf);
    __builtin_amdgcn_s_barrier();
    asm volatile("s_waitcnt lgkmcnt(0)" ::: "memory");
    __builtin_amdgcn_sched_barrier(0);
    __builtin_amdgcn_s_setprio(1);
#pragma unroll
    for (int m = 0; m < 4; ++m)
#pragma unroll
      for (int n = 0; n < 2; ++n) {
        acc[m][n] = __builtin_amdgcn_mfma_f32_16x16x32_bf16(af[m][0], bfr[n][0], acc[m][n], 0, 0, 0);
        acc[m][n] = __builtin_amdgcn_mfma_f32_16x16x32_bf16(af[m][1], bfr[n][1], acc[m][n], 0, 0, 0);
      }
    __builtin_amdgcn_s_setprio(0);
    __builtin_amdgcn_s_barrier();
    __builtin_amdgcn_sched_barrier(0);
    // ---- P1: reads B(n2-3) [4]; MFMA q(0,1) ----
#pragma unroll
    for (int n = 2; n < 4; ++n) {
      bfr[n][0] = *(const bf16x8*)(Bb + n * 2048 + arow);
      bfr[n][1] = *(const bf16x8*)(Bb + n * 2048 + (arow ^ 64));
    }
    __builtin_amdgcn_s_barrier();
    asm volatile("s_waitcnt lgkmcnt(0)" ::: "memory");
    __builtin_amdgcn_sched_barrier(0);
    __builtin_amdgcn_s_setprio(1);
#pragma unroll
    for (int m = 0; m < 4; ++m)
#pragma unroll
      for (int n = 2; n < 4; ++n) {
        acc[m][n] = __builtin_amdgcn_mfma_f32_16x16x32_bf16(af[m][0], bfr[n][0], acc[m][n], 0, 0, 0);
        acc[m][n] = __builtin_amdgcn_mfma_f32_16x16x32_bf16(af[m][1], bfr[n][1], acc[m][n], 0, 0, 0);
      }
    __builtin_amdgcn_s_setprio(0);
    __builtin_amdgcn_s_barrier();
    __builtin_amdgcn_sched_barrier(0);
    // ---- P2: reads A(m4-7) [8]; stage B0(kt+2); MFMA q(1,0) ----
#pragma unroll
    for (int m = 0; m < 4; ++m) {
      af[m][0] = *(const bf16x8*)(Ab + (4 + m) * 2048 + arow);
      af[m][1] = *(const bf16x8*)(Ab + (4 + m) * 2048 + (arow ^ 64));
    }
    if (kt + 2 < NT) stageB1(0, cbuf);
    __builtin_amdgcn_s_barrier();
    asm volatile("s_waitcnt lgkmcnt(0)" ::: "memory");
    __builtin_amdgcn_sched_barrier(0);
    __builtin_amdgcn_s_setprio(1);
#pragma unroll
    for (int m = 0; m < 4; ++m)
#pragma unroll
      for (int n = 0; n < 2; ++n) {
        acc[4 + m][n] = __builtin_amdgcn_mfma_f32_16x16x32_bf16(af[m][0], bfr[n][0], acc[4 + m][n], 0, 0, 0);
        acc[4 + m][n] = __builtin_amdgcn_mfma_f32_16x16x32_bf16(af[m][1], bfr[n][1], acc[4 + m][n], 0, 0, 0);
      }
    __builtin_amdgcn_s_setprio(0);
    __builtin_amdgcn_s_barrier();
    __builtin_amdgcn_sched_barrier(0);
    // ---- P3: no reads; stage A0+A1(kt+2); MFMA q(1,1); boundary vmcnt ----
    if (kt + 2 < NT) stageA2(cbuf);
    __builtin_amdgcn_s_barrier();
    asm volatile("s_waitcnt lgkmcnt(0)" ::: "memory");
    __builtin_amdgcn_sched_barrier(0);
    __builtin_amdgcn_s_setprio(1);
#pragma unroll
    for (int m = 0; m < 4; ++m)
#pragma unroll
      for (int n = 2; n < 4; ++n) {
        acc[4 + m][n] = __builtin_amdgcn_mfma_f32_16x16x32_bf16(af[m][0], bfr[n][0], acc[4 + m][n], 0, 0, 0);
        acc[4 + m][n] = __builtin_amdgcn_mfma_f32_16x16x32_bf16(af[m][1], bfr[n][1], acc[4 + m][n], 0, 0, 0);
      }
    __builtin_amdgcn_s_setprio(0);
    if (kt < NT - 2)      asm volatile("s_waitcnt vmcnt(6)" ::: "memory");
    else if (kt == NT - 2) asm volatile("s_waitcnt vmcnt(0)" ::: "memory");
    __builtin_amdgcn_s_barrier();
    __builtin_amdgcn_sched_barrier(0);
  }

  const int rbase = by * BMT + wm * (BMT / 2) + (gk << 2);
  const int cbase = bx * 256 + wn * 64 + lane15;
#pragma unroll
  for (int m = 0; m < MR; ++m)
#pragma unroll
    for (int n = 0; n < 4; ++n) {
      const int col = cbase + n * 16;
      if (OMODE == 4) {
        const float bval = (bz == 0 ? bias : bz == 1 ? b1 : b2)[col];
#pragma unroll
        for (int r = 0; r < 4; ++r) {
          const int rowg = rbase + m * 16 + r;
          const float v = acc[m][n][r] + bval;
          if (bz == 0)
            ((u16*)Cv)[(size_t)rowg * N + col] = f2bf(v);
          else if (bz == 1)
            C1[(size_t)rowg * N + col] = f2bf(v);
          else  // V: write transposed Vt[b][col][s]
            C2[(size_t)(rowg >> 11) * ((size_t)DE * SEQ) +
               (size_t)col * SEQ + (rowg & 2047)] = f2bf(v);
        }
      } else {
        const float bval = HAS_BIAS ? bias[col] : 0.f;
#pragma unroll
        for (int r = 0; r < 4; ++r) {
          const int rowg = rbase + m * 16 + r;
          const float v = acc[m][n][r] * scale + bval;
          if (OMODE == 0)
            ((float*)Cv)[(size_t)bz * sC + (size_t)rowg * N + col] = v;
          else
            ((u16*)Cv)[(size_t)bz * sC + (size_t)rowg * N + col] = f2bf(v);
        }
      }
    }
}

extern "C" void kernel_launch(void* const* d_in, const int* in_sizes, int n_in,
                              void* d_out, int out_size, void* d_ws, size_t ws_size,
                              hipStream_t stream) {
  const float* x  = (const float*)d_in[0];
  const float* Wq = (const float*)d_in[1];
  const float* bq = (const float*)d_in[2];
  const float* Wk = (const float*)d_in[3];
  const float* bk = (const float*)d_in[4];
  const float* Wv = (const float*)d_in[5];
  const float* bv = (const float*)d_in[6];
  const float* Wo = (const float*)d_in[7];
  const float* bo = (const float*)d_in[8];

  // workspace (bytes) — total 142,606,336. bf16 logits/P [8][2048][2048]
  // = 67,108,864 B live in d_out, dead before the final Wo GEMM overwrites it.
  const size_t NEED = 142606336;
  if (ws_size < NEED) return;
  char* ws = (char*)d_ws;
  u16* x_bf = (u16*)(ws);                   // 33,554,432
  u16* q_bf = (u16*)(ws + 33554432);        // 33,554,432 (Q; later attn output)
  u16* k_bf = (u16*)(ws + 67108864);        // 33,554,432
  u16* vt   = (u16*)(ws + 100663296);       // 33,554,432 (V^T per batch [d][s])
  u16* wt   = (u16*)(ws + 134217728);       // 8,388,608  (4 x 2MB: q,k,v,o)
  u16* lgP  = (u16*)d_out;                  // 67,108,864 (logits/P scratch)
  u16* wt_o = wt + 3145728;

  dim3 tb(32, 8);
  const size_t sQ = (size_t)SEQ * DE;   // per-batch Q/K/attn/vt stride
  const size_t sL = (size_t)SEQ * SEQ;  // per-batch logits stride

  // 1. x -> bf16
  cvt_f32_bf16<<<16384, 256, 0, stream>>>(x, x_bf, (NB * SEQ * DIN) / 4);
  // 2. all four weight transposes in ONE launch (fp32 -> bf16, [K,N] -> [N,K])
  transpose_w4<<<dim3(32, 32, 4), tb, 0, stream>>>(Wq, Wk, Wv, Wo, wt);
  // 3. QKV projections in ONE dispatch: gridDim.z selects weight/bias/output
  //    (z-batched — per-block work identical to 3 separate dispatches)
  gemmph<256, 4, true><<<dim3(4, 64, 3), 512, 0, stream>>>(x_bf, wt, q_bf, bq,
      16384, 1024, 1024, 0, 0, 0, 1.f, k_bf, vt, bk, bv);
  // 4. logits = Q @ K^T * (1/32) -> bf16 in d_out, ALL batches (512 blocks)
  gemmph<256, 1, false><<<dim3(8, 8, 8), 512, 0, stream>>>(q_bf, k_bf, lgP,
      nullptr, 2048, 2048, 1024, sQ, sQ, sL, 0.03125f,
      nullptr, nullptr, nullptr, nullptr);
  // 5. in-place row softmax over all 16384 rows
  softmax_rows_bf16<<<16384, 256, 0, stream>>>(lgP);
  // 6. values = P @ Vt^T -> overwrite q_bf (Q dead), 256 blocks, K=2048
  gemmph<256, 1, false><<<dim3(4, 8, 8), 512, 0, stream>>>(lgP, vt, q_bf,
      nullptr, 2048, 1024, 2048, sL, sQ, sQ, 1.f,
      nullptr, nullptr, nullptr, nullptr);
  // 7. out = attn @ Wo + bo (fp32) -> d_out (overwrites dead P)
  gemmph<256, 0, true><<<dim3(4, 64, 1), 512, 0, stream>>>(q_bf, wt_o, d_out, bo,
      16384, 1024, 1024, 0, 0, 0, 1.f, nullptr, nullptr, nullptr, nullptr);

  (void)in_sizes; (void)n_in; (void)out_size; (void)ws_size;
}

// Round 16
// 333.707 us; speedup vs baseline: 1.1586x; 1.1586x over previous
//
#include <hip/hip_runtime.h>

#define DIN 1024
#define DE  1024
#define SEQ 2048
#define NB  8

typedef __bf16 bf16x8 __attribute__((ext_vector_type(8)));
typedef float  f32x4  __attribute__((ext_vector_type(4)));
typedef unsigned short u16;
typedef u16 u16x8 __attribute__((ext_vector_type(8)));
typedef u16 u16x4 __attribute__((ext_vector_type(4)));

__device__ __forceinline__ u16 f2bf(float f) {
  unsigned u = __builtin_bit_cast(unsigned, f);
  return (u16)((u + 0x7FFFu + ((u >> 16) & 1u)) >> 16);
}
__device__ __forceinline__ float bf2f(u16 h) {
  return __builtin_bit_cast(float, (unsigned)h << 16);
}

typedef __attribute__((address_space(1))) const unsigned char g_u8;
typedef __attribute__((address_space(3))) unsigned char l_u8;
__device__ __forceinline__ void gload16(const void* g, void* l) {
  __builtin_amdgcn_global_load_lds((g_u8*)g, (l_u8*)l, 16, 0, 0);
}

// ---------------- convert fp32 -> bf16 (vectorized) ----------------
__global__ __launch_bounds__(256) void cvt_f32_bf16(const float* __restrict__ in,
                                                    u16* __restrict__ out, int n4) {
  int i = blockIdx.x * 256 + threadIdx.x;
  if (i >= n4) return;
  float4 v = ((const float4*)in)[i];
  u16x4 o;
  o[0] = f2bf(v.x); o[1] = f2bf(v.y); o[2] = f2bf(v.z); o[3] = f2bf(v.w);
  ((u16x4*)out)[i] = o;
}

// ---------------- transpose W [K=1024][N=1024] fp32 -> Wt [N][K] bf16 ----------------
__global__ __launch_bounds__(256) void transpose_w(const float* __restrict__ W,
                                                   u16* __restrict__ Wt) {
  __shared__ float t[32][33];
  const int tx = threadIdx.x, ty = threadIdx.y;
  const int bx = blockIdx.x * 32, by = blockIdx.y * 32;
#pragma unroll
  for (int i = 0; i < 4; ++i)
    t[ty + i * 8][tx] = W[(size_t)(by + ty + i * 8) * 1024 + bx + tx];
  __syncthreads();
#pragma unroll
  for (int i = 0; i < 4; ++i)
    Wt[(size_t)(bx + ty + i * 8) * 1024 + by + tx] = f2bf(t[tx][ty + i * 8]);
}

// ---------------- in-place row softmax on bf16 [rows][2048] ----------------
__global__ __launch_bounds__(256) void softmax_rows_bf16(u16* __restrict__ P) {
  const size_t row = blockIdx.x;
  u16* pr = P + row * 2048 + (size_t)threadIdx.x * 8;
  u16x8 v = *(const u16x8*)pr;
  float x[8];
#pragma unroll
  for (int j = 0; j < 8; ++j) x[j] = bf2f(v[j]);
  float m = x[0];
#pragma unroll
  for (int j = 1; j < 8; ++j) m = fmaxf(m, x[j]);
#pragma unroll
  for (int off = 32; off; off >>= 1) m = fmaxf(m, __shfl_xor(m, off));
  __shared__ float rm[4], rs[4];
  const int lane = threadIdx.x & 63, wid = threadIdx.x >> 6;
  if (lane == 0) rm[wid] = m;
  __syncthreads();
  m = fmaxf(fmaxf(rm[0], rm[1]), fmaxf(rm[2], rm[3]));
  float s = 0.f;
#pragma unroll
  for (int j = 0; j < 8; ++j) { x[j] = __expf(x[j] - m); s += x[j]; }
#pragma unroll
  for (int off = 32; off; off >>= 1) s += __shfl_xor(s, off);
  if (lane == 0) rs[wid] = s;
  __syncthreads();
  s = (rs[0] + rs[1]) + (rs[2] + rs[3]);
  const float inv = 1.f / s;
  u16x8 o;
#pragma unroll
  for (int j = 0; j < 8; ++j) o[j] = f2bf(x[j] * inv);
  *(u16x8*)pr = o;
}

// ============ m201-style phase-scheduled GEMM: C = A[M,K] * Bt[N,K]^T ============
// 256x256 tile (BMT=256), BK=64, double-buffered LDS, 8 waves (2Mx4N), phases of
// {ds_read ∥ stage half-tile -> s_barrier -> lgkmcnt(0) -> 16 MFMA -> s_barrier},
// one counted vmcnt(6) per K-tile (0 only at drain). XOR-swizzled LDS via
// pre-swizzled global staging source (measured 0 bank conflicts, r6-r15).
// OMODE: 0=fp32, 1=bf16, 2=bf16 scattered Vt[b][col][s].
template <int BMT, int OMODE, bool HAS_BIAS>
__global__ __launch_bounds__(512, 1) void gemmph(
    const u16* __restrict__ A, const u16* __restrict__ Bt, void* __restrict__ Cv,
    const float* __restrict__ bias, int M, int N, int K,
    size_t sA, size_t sB, size_t sC, float scale) {
  constexpr int ABYTES = BMT * 128;
  constexpr int AHALF  = ABYTES / 2;
  constexpr int BUFB   = ABYTES + 32768;
  constexpr int LA     = AHALF / 8192;
  constexpr int MR     = BMT / 32;
  __shared__ __align__(16) char lds8[2 * BUFB];
  const int tid = threadIdx.x, lane = tid & 63, wid = tid >> 6;
  const int wm = wid >> 2, wn = wid & 3;
  const int lane15 = lane & 15, gk = lane >> 4;

  const int gx = gridDim.x, gy = gridDim.y;
  int lin = blockIdx.x + gx * (blockIdx.y + gy * blockIdx.z);
  const int nwg = gx * gy * (int)gridDim.z;
  const int q = nwg >> 3, r8 = nwg & 7;
  const int xcd = lin & 7, idx = lin >> 3;
  lin = (xcd < r8 ? xcd * (q + 1) : r8 * (q + 1) + (xcd - r8) * q) + idx;
  const int bz = lin / (gx * gy);
  const int rem = lin - bz * (gx * gy);
  const int by = rem / gx, bx = rem - (rem / gx) * gx;

  const char* Ag = (const char*)(A + (size_t)bz * sA + (size_t)by * BMT * K);
  const char* Bg = (const char*)(Bt + (size_t)bz * sB + (size_t)bx * 256 * K);
  const size_t Kb = (size_t)K * 2;

  const int spr = tid >> 3;
  const int sg = (tid & 7) ^ (spr & 7);
  const char* srcA[2][2];
  const char* srcB[2][2];
#pragma unroll
  for (int h = 0; h < 2; ++h) {
#pragma unroll
    for (int j = 0; j < LA; ++j)
      srcA[h][j] = Ag + (size_t)(h * (BMT / 2) + j * 64 + spr) * Kb + sg * 16;
#pragma unroll
    for (int j = 0; j < 2; ++j)
      srcB[h][j] = Bg + (size_t)(h * 128 + j * 64 + spr) * Kb + sg * 16;
  }

  auto stageA2 = [&](int dbuf) {
#pragma unroll
    for (int h = 0; h < 2; ++h) {
      char* d = lds8 + dbuf * BUFB + h * AHALF + tid * 16;
#pragma unroll
      for (int j = 0; j < LA; ++j) { gload16(srcA[h][j], d + j * 8192); srcA[h][j] += 128; }
    }
  };
  auto stageB1 = [&](int h, int dbuf) {
    char* d = lds8 + dbuf * BUFB + ABYTES + h * 16384 + tid * 16;
    gload16(srcB[h][0], d);        srcB[h][0] += 128;
    gload16(srcB[h][1], d + 8192); srcB[h][1] += 128;
  };

  const int arow = lane15 * 128 + ((gk ^ (lane15 & 7)) << 4);

  f32x4 acc[MR][4] = {};
  const int NT = K >> 6;

  stageA2(0); stageB1(0, 0); stageB1(1, 0);
  stageB1(0, 1); stageA2(1);
  asm volatile("s_waitcnt vmcnt(6)" ::: "memory");
  __builtin_amdgcn_s_barrier();
  __builtin_amdgcn_sched_barrier(0);

  for (int kt = 0; kt < NT; ++kt) {
    const char* Ab = lds8 + (kt & 1) * BUFB + wm * AHALF;
    const char* Bb = lds8 + (kt & 1) * BUFB + ABYTES + (wn >> 1) * 16384 + (wn & 1) * 8192;
    const int nbuf = (kt + 1) & 1;
    const int cbuf = kt & 1;
    bf16x8 af[4][2], bfr[4][2];

    // ---- P0: reads A(m0-3)+B(n0-1) [12]; stage B1(kt+1); MFMA q(0,0) ----
#pragma unroll
    for (int m = 0; m < 4; ++m) {
      af[m][0] = *(const bf16x8*)(Ab + m * 2048 + arow);
      af[m][1] = *(const bf16x8*)(Ab + m * 2048 + (arow ^ 64));
    }
#pragma unroll
    for (int n = 0; n < 2; ++n) {
      bfr[n][0] = *(const bf16x8*)(Bb + n * 2048 + arow);
      bfr[n][1] = *(const bf16x8*)(Bb + n * 2048 + (arow ^ 64));
    }
    if (kt + 1 < NT) stageB1(1, nbuf);
    __builtin_amdgcn_s_barrier();
    asm volatile("s_waitcnt lgkmcnt(0)" ::: "memory");
    __builtin_amdgcn_sched_barrier(0);
    __builtin_amdgcn_s_setprio(1);
#pragma unroll
    for (int m = 0; m < 4; ++m)
#pragma unroll
      for (int n = 0; n < 2; ++n) {
        acc[m][n] = __builtin_amdgcn_mfma_f32_16x16x32_bf16(af[m][0], bfr[n][0], acc[m][n], 0, 0, 0);
        acc[m][n] = __builtin_amdgcn_mfma_f32_16x16x32_bf16(af[m][1], bfr[n][1], acc[m][n], 0, 0, 0);
      }
    __builtin_amdgcn_s_setprio(0);
    __builtin_amdgcn_s_barrier();
    __builtin_amdgcn_sched_barrier(0);
    // ---- P1: reads B(n2-3) [4]; MFMA q(0,1) ----
#pragma unroll
    for (int n = 2; n < 4; ++n) {
      bfr[n][0] = *(const bf16x8*)(Bb + n * 2048 + arow);
      bfr[n][1] = *(const bf16x8*)(Bb + n * 2048 + (arow ^ 64));
    }
    __builtin_amdgcn_s_barrier();
    asm volatile("s_waitcnt lgkmcnt(0)" ::: "memory");
    __builtin_amdgcn_sched_barrier(0);
    __builtin_amdgcn_s_setprio(1);
#pragma unroll
    for (int m = 0; m < 4; ++m)
#pragma unroll
      for (int n = 2; n < 4; ++n) {
        acc[m][n] = __builtin_amdgcn_mfma_f32_16x16x32_bf16(af[m][0], bfr[n][0], acc[m][n], 0, 0, 0);
        acc[m][n] = __builtin_amdgcn_mfma_f32_16x16x32_bf16(af[m][1], bfr[n][1], acc[m][n], 0, 0, 0);
      }
    __builtin_amdgcn_s_setprio(0);
    __builtin_amdgcn_s_barrier();
    __builtin_amdgcn_sched_barrier(0);
    // ---- P2: reads A(m4-7) [8]; stage B0(kt+2); MFMA q(1,0) ----
#pragma unroll
    for (int m = 0; m < 4; ++m) {
      af[m][0] = *(const bf16x8*)(Ab + (4 + m) * 2048 + arow);
      af[m][1] = *(const bf16x8*)(Ab + (4 + m) * 2048 + (arow ^ 64));
    }
    if (kt + 2 < NT) stageB1(0, cbuf);
    __builtin_amdgcn_s_barrier();
    asm volatile("s_waitcnt lgkmcnt(0)" ::: "memory");
    __builtin_amdgcn_sched_barrier(0);
    __builtin_amdgcn_s_setprio(1);
#pragma unroll
    for (int m = 0; m < 4; ++m)
#pragma unroll
      for (int n = 0; n < 2; ++n) {
        acc[4 + m][n] = __builtin_amdgcn_mfma_f32_16x16x32_bf16(af[m][0], bfr[n][0], acc[4 + m][n], 0, 0, 0);
        acc[4 + m][n] = __builtin_amdgcn_mfma_f32_16x16x32_bf16(af[m][1], bfr[n][1], acc[4 + m][n], 0, 0, 0);
      }
    __builtin_amdgcn_s_setprio(0);
    __builtin_amdgcn_s_barrier();
    __builtin_amdgcn_sched_barrier(0);
    // ---- P3: no reads; stage A0+A1(kt+2); MFMA q(1,1); boundary vmcnt ----
    if (kt + 2 < NT) stageA2(cbuf);
    __builtin_amdgcn_s_barrier();
    asm volatile("s_waitcnt lgkmcnt(0)" ::: "memory");
    __builtin_amdgcn_sched_barrier(0);
    __builtin_amdgcn_s_setprio(1);
#pragma unroll
    for (int m = 0; m < 4; ++m)
#pragma unroll
      for (int n = 2; n < 4; ++n) {
        acc[4 + m][n] = __builtin_amdgcn_mfma_f32_16x16x32_bf16(af[m][0], bfr[n][0], acc[4 + m][n], 0, 0, 0);
        acc[4 + m][n] = __builtin_amdgcn_mfma_f32_16x16x32_bf16(af[m][1], bfr[n][1], acc[4 + m][n], 0, 0, 0);
      }
    __builtin_amdgcn_s_setprio(0);
    if (kt < NT - 2)      asm volatile("s_waitcnt vmcnt(6)" ::: "memory");
    else if (kt == NT - 2) asm volatile("s_waitcnt vmcnt(0)" ::: "memory");
    __builtin_amdgcn_s_barrier();
    __builtin_amdgcn_sched_barrier(0);
  }

  const int rbase = by * BMT + wm * (BMT / 2) + (gk << 2);
  const int cbase = bx * 256 + wn * 64 + lane15;
#pragma unroll
  for (int m = 0; m < MR; ++m)
#pragma unroll
    for (int n = 0; n < 4; ++n) {
      const int col = cbase + n * 16;
      const float bval = HAS_BIAS ? bias[col] : 0.f;
#pragma unroll
      for (int r = 0; r < 4; ++r) {
        const int rowg = rbase + m * 16 + r;
        const float v = acc[m][n][r] * scale + bval;
        if (OMODE == 0)
          ((float*)Cv)[(size_t)bz * sC + (size_t)rowg * N + col] = v;
        else if (OMODE == 1)
          ((u16*)Cv)[(size_t)bz * sC + (size_t)rowg * N + col] = f2bf(v);
        else
          ((u16*)Cv)[(size_t)(rowg >> 11) * ((size_t)DE * SEQ) +
                     (size_t)col * SEQ + (rowg & 2047)] = f2bf(v);
      }
    }
}

extern "C" void kernel_launch(void* const* d_in, const int* in_sizes, int n_in,
                              void* d_out, int out_size, void* d_ws, size_t ws_size,
                              hipStream_t stream) {
  const float* x  = (const float*)d_in[0];
  const float* Wq = (const float*)d_in[1];
  const float* bq = (const float*)d_in[2];
  const float* Wk = (const float*)d_in[3];
  const float* bk = (const float*)d_in[4];
  const float* Wv = (const float*)d_in[5];
  const float* bv = (const float*)d_in[6];
  const float* Wo = (const float*)d_in[7];
  const float* bo = (const float*)d_in[8];

  // workspace (bytes) — total 142,606,336. bf16 logits/P [8][2048][2048]
  // = 67,108,864 B live in d_out, dead before the final Wo GEMM overwrites it.
  const size_t NEED = 142606336;
  if (ws_size < NEED) return;
  char* ws = (char*)d_ws;
  u16* x_bf = (u16*)(ws);                   // 33,554,432
  u16* q_bf = (u16*)(ws + 33554432);        // 33,554,432 (Q; later attn output)
  u16* k_bf = (u16*)(ws + 67108864);        // 33,554,432
  u16* vt   = (u16*)(ws + 100663296);       // 33,554,432 (V^T per batch [d][s])
  u16* wt   = (u16*)(ws + 134217728);       // 8,388,608  (4 x 2MB: q,k,v,o)
  u16* lgP  = (u16*)d_out;                  // 67,108,864 (logits/P scratch)
  u16* wt_q = wt;
  u16* wt_k = wt + 1048576;
  u16* wt_v = wt + 2097152;
  u16* wt_o = wt + 3145728;

  dim3 tb(32, 8);
  const size_t sQ = (size_t)SEQ * DE;   // per-batch Q/K/attn/vt stride
  const size_t sL = (size_t)SEQ * SEQ;  // per-batch logits stride

  // 1. x -> bf16
  cvt_f32_bf16<<<16384, 256, 0, stream>>>(x, x_bf, (NB * SEQ * DIN) / 4);
  // 2. weight transposes (fp32 -> bf16, [K,N] -> [N,K])
  transpose_w<<<dim3(32, 32), tb, 0, stream>>>(Wq, wt_q);
  transpose_w<<<dim3(32, 32), tb, 0, stream>>>(Wk, wt_k);
  transpose_w<<<dim3(32, 32), tb, 0, stream>>>(Wv, wt_v);
  transpose_w<<<dim3(32, 32), tb, 0, stream>>>(Wo, wt_o);
  // 3. QKV projections: [16384,1024] @ [1024,1024]^T + bias
  gemmph<256, 1, true><<<dim3(4, 64, 1), 512, 0, stream>>>(x_bf, wt_q, q_bf, bq,
      16384, 1024, 1024, 0, 0, 0, 1.f);
  gemmph<256, 1, true><<<dim3(4, 64, 1), 512, 0, stream>>>(x_bf, wt_k, k_bf, bk,
      16384, 1024, 1024, 0, 0, 0, 1.f);
  gemmph<256, 2, true><<<dim3(4, 64, 1), 512, 0, stream>>>(x_bf, wt_v, vt, bv,
      16384, 1024, 1024, 0, 0, 0, 1.f);
  // 4. logits = Q @ K^T * (1/32) -> bf16 in d_out, ALL batches (512 blocks)
  gemmph<256, 1, false><<<dim3(8, 8, 8), 512, 0, stream>>>(q_bf, k_bf, lgP,
      nullptr, 2048, 2048, 1024, sQ, sQ, sL, 0.03125f);
  // 5. in-place row softmax over all 16384 rows
  softmax_rows_bf16<<<16384, 256, 0, stream>>>(lgP);
  // 6. values = P @ Vt^T -> overwrite q_bf (Q dead), 256 blocks, K=2048
  gemmph<256, 1, false><<<dim3(4, 8, 8), 512, 0, stream>>>(lgP, vt, q_bf,
      nullptr, 2048, 1024, 2048, sL, sQ, sQ, 1.f);
  // 7. out = attn @ Wo + bo (fp32) -> d_out (overwrites dead P)
  gemmph<256, 0, true><<<dim3(4, 64, 1), 512, 0, stream>>>(q_bf, wt_o, d_out, bo,
      16384, 1024, 1024, 0, 0, 0, 1.f);

  (void)in_sizes; (void)n_in; (void)out_size; (void)ws_size;
}